// Round 4
// baseline (442.425 us; speedup 1.0000x reference)
//
#include <hip/hip_runtime.h>
#include <hip/hip_bf16.h>
#include <stdint.h>
#include <stddef.h>

// GCNConv: out = S (X W^T + 1 b^T), S = D^-1/2 (A+I) D^-1/2
// Fast paths: Xb = bf16(X) [if ws allows]; H = Xb Wb^T + b via async MFMA GEMM
//   (128x128, BK=32, global_load_lds, XCD swizzle), H pitch padded to 1088
//   elems (2176B = 17 cache lines) to kill pow2 set-aliasing; then
//   column-slab aggregation with XCD-affinity: slab s is processed only by
//   blocks with blockIdx%8 == s%8, so each slab's 2.56MB line-set is filled
//   into exactly ONE XCD's L2 (fills ~41MB total instead of ~8x348MB).
//   Meta (8B col,w) read nontemporally (streaming), out stores nontemporal.
// Fallback (small ws): aggregate-first + strip GEMM.
// Dtypes detected on device: flags[0] x fp32?, flags[1] W fp32?, flags[2] int64 edges?

#define D_DIM 1024
#define HP    1088            // padded H pitch in elements
#define HPB   2176u           // padded H pitch in bytes (17 * 128)
#define SLABW 64              // cols per slab = one 128B line
#define NSLAB (D_DIM / SLABW) // 16

typedef __bf16 bf16x8 __attribute__((ext_vector_type(8)));
typedef __bf16 bf16x4 __attribute__((ext_vector_type(4)));
typedef float  f32x4  __attribute__((ext_vector_type(4)));

#define GLOBAL_AS __attribute__((address_space(1)))
#define LDS_AS    __attribute__((address_space(3)))

static __device__ __forceinline__ void async_load16(const void* g, void* l) {
  __builtin_amdgcn_global_load_lds((GLOBAL_AS void*)(void*)g,
                                   (LDS_AS void*)l, 16, 0, 0);
}

// ---------------- dtype detection ----------------

__global__ void detect_kernel(const unsigned int* __restrict__ xw,
                              const unsigned int* __restrict__ ww,
                              const unsigned int* __restrict__ ew,
                              int* __restrict__ flags) {
  __shared__ int s[3];
  int t = threadIdx.x;
  if (t < 3) s[t] = 0;
  __syncthreads();
  int nx = 0, nw = 0, ze = 0;
  for (int i = t; i < 8192; i += 256) {
    if ((xw[i] & 0x7f80u) == 0x7f80u) nx++;
    if ((ww[i] & 0x7f80u) == 0x7f80u) nw++;
    if (ew[2 * i + 1] == 0u) ze++;
  }
  atomicAdd(&s[0], nx);
  atomicAdd(&s[1], nw);
  atomicAdd(&s[2], ze);
  __syncthreads();
  if (t == 0) {
    flags[0] = (s[0] >= 3) ? 1 : 0;
    flags[1] = (s[1] >= 3) ? 1 : 0;
    flags[2] = (s[2] >= 8000) ? 1 : 0;
  }
}

// ---------------- CSR construction ----------------

__global__ void zero_cnt_kernel(int* cnt, int n) {
  int i = blockIdx.x * blockDim.x + threadIdx.x;
  if (i < n) cnt[i] = 0;
}

__global__ void count_deg_kernel(const void* __restrict__ ei, int E,
                                 const int* __restrict__ flags,
                                 int* __restrict__ cnt) {
  int e = blockIdx.x * blockDim.x + threadIdx.x;
  if (e < E) {
    int r = flags[2] ? (int)((const long long*)ei)[e] : ((const int*)ei)[e];
    atomicAdd(&cnt[r], 1);
  }
}

// Single block, 256 threads; each thread owns a contiguous chunk.
__global__ void scan_kernel(const int* __restrict__ cnt, int n,
                            int* __restrict__ row_ptr, int* __restrict__ cursor,
                            float* __restrict__ dinv) {
  __shared__ int ssum[256];
  const int t = threadIdx.x;
  const int chunk = (n + 255) / 256;
  const int lo = t * chunk;
  const int hi = (lo + chunk < n) ? lo + chunk : n;
  int s = 0;
  for (int i = lo; i < hi; ++i) s += cnt[i];
  ssum[t] = s;
  __syncthreads();
  for (int off = 1; off < 256; off <<= 1) {
    int add = (t >= off) ? ssum[t - off] : 0;
    __syncthreads();
    ssum[t] += add;
    __syncthreads();
  }
  int run = ssum[t] - s;  // exclusive prefix of this thread's chunk
  for (int i = lo; i < hi; ++i) {
    int v = cnt[i];
    row_ptr[i] = run;
    cursor[i]  = run;
    dinv[i] = rsqrtf((float)(v + 1));
    run += v;
  }
  if (t == 255) row_ptr[n] = ssum[255];
}

// emit_w: store packed 8B meta { w:hi32, col:lo32 } (fast path).
// else:   store plain cols (fallback path).
__global__ void scatter_kernel(const void* __restrict__ ei, int E,
                               const int* __restrict__ flags,
                               const float* __restrict__ dinv,
                               int* __restrict__ cursor,
                               int* __restrict__ cols_out,
                               long long* __restrict__ meta, int emit_w) {
  int e = blockIdx.x * blockDim.x + threadIdx.x;
  if (e < E) {
    int r, c;
    if (flags[2]) {
      const long long* p = (const long long*)ei;
      r = (int)p[e]; c = (int)p[e + E];
    } else {
      const int* p = (const int*)ei;
      r = p[e]; c = p[e + E];
    }
    int pos = atomicAdd(&cursor[r], 1);
    if (emit_w) {
      float w = dinv[r] * dinv[c];
      unsigned long long mm =
          ((unsigned long long)__float_as_uint(w) << 32) | (unsigned)c;
      meta[pos] = (long long)mm;
    } else {
      cols_out[pos] = c;
    }
  }
}

// ---------------- canonicalize W (bf16) and bias (fp32) ----------------

__global__ void conv_w_kernel(const void* __restrict__ W,
                              const void* __restrict__ b,
                              const int* __restrict__ flags,
                              unsigned short* __restrict__ Wb,
                              float* __restrict__ biasf) {
  int i = blockIdx.x * blockDim.x + threadIdx.x;  // < 1M
  int wfp = flags[1];
  if (wfp) {
    __bf16 h = (__bf16)((const float*)W)[i];
    Wb[i] = *(unsigned short*)&h;
  } else {
    Wb[i] = ((const unsigned short*)W)[i];
  }
  if (i < D_DIM) {
    biasf[i] = wfp ? ((const float*)b)[i] : (float)((const __bf16*)b)[i];
  }
}

// ---------------- canonicalize X (bf16), faster path only ----------------

__global__ __launch_bounds__(256) void conv_x_kernel(
    const void* __restrict__ X, const int* __restrict__ flags,
    unsigned short* __restrict__ Xb, int total8) {
  int i = blockIdx.x * blockDim.x + threadIdx.x;
  if (i >= total8) return;
  if (!flags[0]) return;  // already bf16: gemm reads X directly
  const float* p = (const float*)X + (size_t)i * 8;
  f32x4 v0 = *(const f32x4*)p;
  f32x4 v1 = *(const f32x4*)(p + 4);
  bf16x8 r;
  r[0] = (__bf16)v0[0]; r[1] = (__bf16)v0[1];
  r[2] = (__bf16)v0[2]; r[3] = (__bf16)v0[3];
  r[4] = (__bf16)v1[0]; r[5] = (__bf16)v1[1];
  r[6] = (__bf16)v1[2]; r[7] = (__bf16)v1[3];
  *(bf16x8*)(Xb + (size_t)i * 8) = r;
}

// ================= FASTEST PATH GEMM =================
// H[M][HP] (bf16, padded pitch) = A * Wb^T + bias, A = bf16 X (Xb or X).
// 128x128 tile, BK=32, 4 waves 2x2, wave = 64x64 via 4x4 mfma 16x16x32.
// Both A and B staged with global_load_lds width=16 (linear LDS, bank-clean).
// 1-D grid, XCD-chunked swizzle, n-tile fastest.

__global__ __launch_bounds__(256) void gemm_xw2_kernel(
    const void* __restrict__ Xv,
    const unsigned short* __restrict__ Xb,
    const unsigned short* __restrict__ Wb,   // [1024][1024] bf16 [o][k]
    const float* __restrict__ biasf,
    const int* __restrict__ flags,
    __hip_bfloat16* __restrict__ H,          // [M][HP] bf16
    int M) {
  __shared__ unsigned short As[128 * 32];
  __shared__ unsigned short Bs[128 * 32];

  const int t    = threadIdx.x;
  const int lane = t & 63;
  const int wave = t >> 6;
  const int wm   = wave >> 1;
  const int wn   = wave & 1;

  const int nwg = gridDim.x;  // mtiles*8, divisible by 8
  const int wg  = (blockIdx.x & 7) * (nwg >> 3) + (blockIdx.x >> 3);
  const int m0  = (wg >> 3) * 128;
  const int n0  = (wg & 7) * 128;

  const unsigned short* Asrc =
      flags[0] ? Xb : (const unsigned short*)Xv;

  f32x4 acc[4][4] = {};

  const int ra = t >> 2;          // staging row 0..63 within half-tile
  const int kc = (t & 3) * 8;     // staging k-chunk (8 elems = 16B)
  int gr0 = m0 + ra;       if (gr0 >= M) gr0 = M - 1;   // clamp: dup row, masked at store
  int gr1 = m0 + 64 + ra;  if (gr1 >= M) gr1 = M - 1;
  const int quad = lane >> 4;
  const int mrow = lane & 15;

  for (int k0 = 0; k0 < D_DIM; k0 += 32) {
    async_load16(Asrc + (size_t)gr0 * D_DIM + k0 + kc, &As[ra * 32 + kc]);
    async_load16(Asrc + (size_t)gr1 * D_DIM + k0 + kc, &As[(ra + 64) * 32 + kc]);
    async_load16(Wb + (size_t)(n0 + ra) * D_DIM + k0 + kc, &Bs[ra * 32 + kc]);
    async_load16(Wb + (size_t)(n0 + ra + 64) * D_DIM + k0 + kc,
                 &Bs[(ra + 64) * 32 + kc]);
    __syncthreads();

    bf16x8 a[4], b[4];
#pragma unroll
    for (int i = 0; i < 4; ++i)
      a[i] = *(const bf16x8*)&As[(wm * 64 + i * 16 + mrow) * 32 + quad * 8];
#pragma unroll
    for (int j = 0; j < 4; ++j)
      b[j] = *(const bf16x8*)&Bs[(wn * 64 + j * 16 + mrow) * 32 + quad * 8];
#pragma unroll
    for (int i = 0; i < 4; ++i)
#pragma unroll
      for (int j = 0; j < 4; ++j)
        acc[i][j] = __builtin_amdgcn_mfma_f32_16x16x32_bf16(a[i], b[j], acc[i][j], 0, 0, 0);
    __syncthreads();
  }

  // epilogue: C/D layout col = lane&15 (=n), row = quad*4+reg (=m)
#pragma unroll
  for (int j = 0; j < 4; ++j) {
    int n = n0 + wn * 64 + j * 16 + mrow;
    float bn = biasf[n];
#pragma unroll
    for (int i = 0; i < 4; ++i) {
      int mb = m0 + wm * 64 + i * 16 + quad * 4;
#pragma unroll
      for (int rg = 0; rg < 4; ++rg) {
        int m = mb + rg;
        if (m < M) H[(size_t)m * HP + n] = __float2bfloat16(acc[i][j][rg] + bn);
      }
    }
  }
}

// ================= FAST PATH GEMM (manual A staging) =================

__global__ __launch_bounds__(256) void gemm_xw_kernel(
    const void* __restrict__ Xv,
    const unsigned short* __restrict__ Wb,   // [1024][1024] bf16 [o][k]
    const float* __restrict__ biasf,
    const int* __restrict__ flags,
    __hip_bfloat16* __restrict__ H,          // [M][HP] bf16
    int M) {
  __shared__ unsigned short As[128 * 32];
  __shared__ unsigned short Bs[128 * 32];

  const int t    = threadIdx.x;
  const int lane = t & 63;
  const int wave = t >> 6;
  const int wm   = wave >> 1;
  const int wn   = wave & 1;
  const int m0   = blockIdx.x * 128;
  const int n0   = blockIdx.y * 128;
  const int xfp  = flags[0];

  f32x4 acc[4][4] = {};

  const int ra = t >> 1;          // A-staging row 0..127
  const int kh = (t & 1) * 16;    // A-staging k-half (16 elems)
  const int rb = t >> 2;          // B-staging row 0..63
  const int kc = (t & 3) * 8;     // B-staging k-chunk (8 elems = 16B)
  const int quad = lane >> 4;
  const int mrow = lane & 15;

  for (int k0 = 0; k0 < D_DIM; k0 += 32) {
    async_load16(Wb + (size_t)(n0 + rb) * D_DIM + k0 + kc, &Bs[rb * 32 + kc]);
    async_load16(Wb + (size_t)(n0 + rb + 64) * D_DIM + k0 + kc,
                 &Bs[(rb + 64) * 32 + kc]);
    bf16x8 lo{}, hi{};
    int gm = m0 + ra;
    if (gm < M) {
      if (xfp) {
        const float* p = (const float*)Xv + (size_t)gm * D_DIM + k0 + kh;
        f32x4 v0 = *(const f32x4*)(p);
        f32x4 v1 = *(const f32x4*)(p + 4);
        f32x4 v2 = *(const f32x4*)(p + 8);
        f32x4 v3 = *(const f32x4*)(p + 12);
        lo[0] = (__bf16)v0[0]; lo[1] = (__bf16)v0[1];
        lo[2] = (__bf16)v0[2]; lo[3] = (__bf16)v0[3];
        lo[4] = (__bf16)v1[0]; lo[5] = (__bf16)v1[1];
        lo[6] = (__bf16)v1[2]; lo[7] = (__bf16)v1[3];
        hi[0] = (__bf16)v2[0]; hi[1] = (__bf16)v2[1];
        hi[2] = (__bf16)v2[2]; hi[3] = (__bf16)v2[3];
        hi[4] = (__bf16)v3[0]; hi[5] = (__bf16)v3[1];
        hi[6] = (__bf16)v3[2]; hi[7] = (__bf16)v3[3];
      } else {
        const unsigned short* p =
            (const unsigned short*)Xv + (size_t)gm * D_DIM + k0 + kh;
        lo = *(const bf16x8*)p;
        hi = *(const bf16x8*)(p + 8);
      }
    }
    *(bf16x8*)&As[ra * 32 + kh]     = lo;
    *(bf16x8*)&As[ra * 32 + kh + 8] = hi;
    __syncthreads();

    bf16x8 a[4], b[4];
#pragma unroll
    for (int i = 0; i < 4; ++i)
      a[i] = *(const bf16x8*)&As[(wm * 64 + i * 16 + mrow) * 32 + quad * 8];
#pragma unroll
    for (int j = 0; j < 4; ++j)
      b[j] = *(const bf16x8*)&Bs[(wn * 64 + j * 16 + mrow) * 32 + quad * 8];
#pragma unroll
    for (int i = 0; i < 4; ++i)
#pragma unroll
      for (int j = 0; j < 4; ++j)
        acc[i][j] = __builtin_amdgcn_mfma_f32_16x16x32_bf16(a[i], b[j], acc[i][j], 0, 0, 0);
    __syncthreads();
  }

#pragma unroll
  for (int j = 0; j < 4; ++j) {
    int n = n0 + wn * 64 + j * 16 + mrow;
    float bn = biasf[n];
#pragma unroll
    for (int i = 0; i < 4; ++i) {
      int mb = m0 + wm * 64 + i * 16 + quad * 4;
#pragma unroll
      for (int rg = 0; rg < 4; ++rg) {
        int m = mb + rg;
        if (m < M) H[(size_t)m * HP + n] = __float2bfloat16(acc[i][j][rg] + bn);
      }
    }
  }
}

// ---- Column-slab aggregation over padded H, XCD-affine ----
// out[i][slab] = dinv[i]^2 H[i][slab] + sum_e w_e H[col_e][slab]
// 16 slabs x 64 cols. All blocks of slab s have blockIdx%8 == s%8, so
// (with round-robin block->XCD dispatch) slab s lives on ONE XCD: its
// 2.56MB line-set is filled into that XCD's 4MB L2 exactly once and all
// gathers for the slab are local L2 hits. 2 passes (slabs 0-7, 8-15).
// Meta is streaming (read once per pass) -> nontemporal, keeps L2 for H.
// Block = 256 thr = 32 nodes x 8 lanes; lane covers 16B of the 128B line.

__global__ __launch_bounds__(256) void aggregate_h_slab_kernel(
    const __hip_bfloat16* __restrict__ H,
    const int* __restrict__ row_ptr,
    const long long* __restrict__ meta,
    const float* __restrict__ dinv,
    const int* __restrict__ flags,
    void* __restrict__ outv, int M, int nodeblks) {
  // decode: blockIdx = pass*(nodeblks*8) + nb*8 + (slab&7); slab = pass*8+(slab&7)
  const int P    = nodeblks << 3;
  const int pass = blockIdx.x / P;
  const int rem  = blockIdx.x - pass * P;
  const int slab = (pass << 3) + (rem & 7);
  const int nb   = rem >> 3;
  const int t    = threadIdx.x;
  const int i    = nb * 32 + (t >> 3);
  if (i >= M) return;
  const int l = t & 7;
  const unsigned co = (unsigned)l * 16u;
  const char* Hs = (const char*)H + (unsigned)slab * 128u;

  float a[8];
  {
    float di = dinv[i];
    float w = di * di;
    bf16x8 v = *(const bf16x8*)(Hs + (unsigned)i * HPB + co);
#pragma unroll
    for (int k = 0; k < 8; ++k) a[k] = w * (float)v[k];
  }

  const int e0 = row_ptr[i], e1 = row_ptr[i + 1];
  int e = e0;
  for (; e + 4 <= e1; e += 4) {
    long long m0 = __builtin_nontemporal_load(meta + e);
    long long m1 = __builtin_nontemporal_load(meta + e + 1);
    long long m2 = __builtin_nontemporal_load(meta + e + 2);
    long long m3 = __builtin_nontemporal_load(meta + e + 3);
    unsigned o0 = (unsigned)(m0 & 0xffffffffLL) * HPB + co;
    unsigned o1 = (unsigned)(m1 & 0xffffffffLL) * HPB + co;
    unsigned o2 = (unsigned)(m2 & 0xffffffffLL) * HPB + co;
    unsigned o3 = (unsigned)(m3 & 0xffffffffLL) * HPB + co;
    float w0 = __uint_as_float((unsigned)((unsigned long long)m0 >> 32));
    float w1 = __uint_as_float((unsigned)((unsigned long long)m1 >> 32));
    float w2 = __uint_as_float((unsigned)((unsigned long long)m2 >> 32));
    float w3 = __uint_as_float((unsigned)((unsigned long long)m3 >> 32));
    bf16x8 u0 = *(const bf16x8*)(Hs + o0);
    bf16x8 u1 = *(const bf16x8*)(Hs + o1);
    bf16x8 u2 = *(const bf16x8*)(Hs + o2);
    bf16x8 u3 = *(const bf16x8*)(Hs + o3);
#pragma unroll
    for (int q = 0; q < 8; ++q) {
      a[q] = fmaf(w0, (float)u0[q],
             fmaf(w1, (float)u1[q],
             fmaf(w2, (float)u2[q],
             fmaf(w3, (float)u3[q], a[q]))));
    }
  }
  for (; e < e1; ++e) {
    long long m0 = __builtin_nontemporal_load(meta + e);
    unsigned o0 = (unsigned)(m0 & 0xffffffffLL) * HPB + co;
    float w0 = __uint_as_float((unsigned)((unsigned long long)m0 >> 32));
    bf16x8 u0 = *(const bf16x8*)(Hs + o0);
#pragma unroll
    for (int q = 0; q < 8; ++q) a[q] = fmaf(w0, (float)u0[q], a[q]);
  }

  if (flags[0]) {
    float* o = (float*)outv + (size_t)i * D_DIM + slab * SLABW + l * 8;
    f32x4 r0, r1;
    r0[0] = a[0]; r0[1] = a[1]; r0[2] = a[2]; r0[3] = a[3];
    r1[0] = a[4]; r1[1] = a[5]; r1[2] = a[6]; r1[3] = a[7];
    __builtin_nontemporal_store(r0, (f32x4*)o);
    __builtin_nontemporal_store(r1, (f32x4*)(o + 4));
  } else {
    __hip_bfloat16* o =
        (__hip_bfloat16*)outv + (size_t)i * D_DIM + slab * SLABW + l * 8;
    bf16x8 r;
#pragma unroll
    for (int k = 0; k < 8; ++k) r[k] = (__bf16)a[k];
    __builtin_nontemporal_store(*(f32x4*)&r, (f32x4*)o);
  }
}

// ================= FALLBACK PATH (R4, proven) =================

__global__ __launch_bounds__(256) void aggregate_x_kernel(
    const void* __restrict__ X,
    const int* __restrict__ row_ptr,
    const int* __restrict__ cols,
    const float* __restrict__ dinv,
    const int* __restrict__ flags,
    float* __restrict__ rowsum,
    void* __restrict__ Y) {
  const int i  = blockIdx.x;
  const int c0 = threadIdx.x * 4;
  const float di = dinv[i];
  const int e0 = row_ptr[i], e1 = row_ptr[i + 1];
  float wsum = di * di;
  float a0, a1, a2, a3;

  if (flags[0]) {
    const float* Xf = (const float*)X;
    f32x4 v = *(const f32x4*)(Xf + (size_t)i * D_DIM + c0);
    a0 = wsum * v[0]; a1 = wsum * v[1]; a2 = wsum * v[2]; a3 = wsum * v[3];
    for (int e = e0; e < e1; ++e) {
      int c = cols[e];
      float w = di * dinv[c];
      wsum += w;
      f32x4 u = *(const f32x4*)(Xf + (size_t)c * D_DIM + c0);
      a0 += w * u[0]; a1 += w * u[1]; a2 += w * u[2]; a3 += w * u[3];
    }
    f32x4 r; r[0] = a0; r[1] = a1; r[2] = a2; r[3] = a3;
    *(f32x4*)((float*)Y + (size_t)i * D_DIM + c0) = r;
  } else {
    const __hip_bfloat16* Xb = (const __hip_bfloat16*)X;
    bf16x4 v = *(const bf16x4*)(Xb + (size_t)i * D_DIM + c0);
    a0 = wsum * (float)v[0]; a1 = wsum * (float)v[1];
    a2 = wsum * (float)v[2]; a3 = wsum * (float)v[3];
    for (int e = e0; e < e1; ++e) {
      int c = cols[e];
      float w = di * dinv[c];
      wsum += w;
      bf16x4 u = *(const bf16x4*)(Xb + (size_t)c * D_DIM + c0);
      a0 += w * (float)u[0]; a1 += w * (float)u[1];
      a2 += w * (float)u[2]; a3 += w * (float)u[3];
    }
    bf16x4 r;
    r[0] = (__bf16)a0; r[1] = (__bf16)a1; r[2] = (__bf16)a2; r[3] = (__bf16)a3;
    *(bf16x4*)((__hip_bfloat16*)Y + (size_t)i * D_DIM + c0) = r;
  }
  if (threadIdx.x == 0) rowsum[i] = wsum;
}

__global__ __launch_bounds__(256) void strip_gemm_kernel(
    const void* __restrict__ Yv,
    const unsigned short* __restrict__ Wb,
    const float* __restrict__ biasf,
    const float* __restrict__ rowsum,
    const int* __restrict__ flags,
    void* __restrict__ outv) {
  __shared__ unsigned short Ys[32 * 1024];

  const int t    = threadIdx.x;
  const int lane = t & 63;
  const int wave = t >> 6;
  const int m0   = blockIdx.x * 32;
  const int ofp  = flags[0];

  if (ofp) {
    const float* Yf = (const float*)Yv;
    for (int idx = t; idx < 32 * 128; idx += 256) {
      int r = idx >> 7, c = idx & 127;
      const float* p = Yf + (size_t)(m0 + r) * D_DIM + c * 8;
      f32x4 lo = *(const f32x4*)p;
      f32x4 hi = *(const f32x4*)(p + 4);
      bf16x8 v;
      v[0] = (__bf16)lo[0]; v[1] = (__bf16)lo[1];
      v[2] = (__bf16)lo[2]; v[3] = (__bf16)lo[3];
      v[4] = (__bf16)hi[0]; v[5] = (__bf16)hi[1];
      v[6] = (__bf16)hi[2]; v[7] = (__bf16)hi[3];
      int sc = c ^ (r & 15);
      *(bf16x8*)&Ys[r * 1024 + sc * 8] = v;
    }
  } else {
    const __hip_bfloat16* Yb = (const __hip_bfloat16*)Yv;
    for (int idx = t; idx < 32 * 128; idx += 256) {
      int r = idx >> 7, c = idx & 127;
      bf16x8 v = *(const bf16x8*)(Yb + (size_t)(m0 + r) * D_DIM + c * 8);
      int sc = c ^ (r & 15);
      *(bf16x8*)&Ys[r * 1024 + sc * 8] = v;
    }
  }
  __syncthreads();

  const int quad = lane >> 4;
  const int mrow = lane & 15;

  for (int nb = 0; nb < 4; ++nb) {
    f32x4 acc[2][4] = {};
    for (int k0 = 0; k0 < D_DIM; k0 += 32) {
      const int cbase = k0 >> 3;
      bf16x8 a[2], b[4];
#pragma unroll
      for (int i = 0; i < 2; ++i) {
        int m = i * 16 + mrow;
        int sc = (cbase + quad) ^ mrow;
        a[i] = *(const bf16x8*)&Ys[m * 1024 + sc * 8];
      }
#pragma unroll
      for (int j = 0; j < 4; ++j) {
        int n = wave * 256 + nb * 64 + j * 16 + mrow;
        b[j] = *(const bf16x8*)(Wb + (size_t)n * D_DIM + k0 + quad * 8);
      }
#pragma unroll
      for (int i = 0; i < 2; ++i)
#pragma unroll
        for (int j = 0; j < 4; ++j)
          acc[i][j] = __builtin_amdgcn_mfma_f32_16x16x32_bf16(a[i], b[j], acc[i][j], 0, 0, 0);
    }
#pragma unroll
    for (int j = 0; j < 4; ++j) {
      int n = wave * 256 + nb * 64 + j * 16 + mrow;
      float bn = biasf[n];
#pragma unroll
      for (int i = 0; i < 2; ++i) {
        int mb = m0 + i * 16 + quad * 4;
#pragma unroll
        for (int rg = 0; rg < 4; ++rg) {
          int m = mb + rg;
          float val = acc[i][j][rg] + rowsum[m] * bn;
          if (ofp) ((float*)outv)[(size_t)m * D_DIM + n] = val;
          else ((__hip_bfloat16*)outv)[(size_t)m * D_DIM + n] = __float2bfloat16(val);
        }
      }
    }
  }
}

// ---------------- launch ----------------

extern "C" void kernel_launch(void* const* d_in, const int* in_sizes, int n_in,
                              void* d_out, int out_size, void* d_ws, size_t ws_size,
                              hipStream_t stream) {
  const void* x    = d_in[0];
  const void* ei   = d_in[1];
  const void* Wm   = d_in[2];
  const void* bias = d_in[3];

  const int E = in_sizes[1] / 2;
  const int M = in_sizes[0] / D_DIM;

  char* ws = (char*)d_ws;
  const size_t KB = 1024, MB = 1024 * 1024;

  // fast-path layout (runtime offsets; meta sized by E)
  const size_t off_flags = 0;
  const size_t off_cnt   = 4 * KB;
  const size_t off_biasf = 96 * KB;
  const size_t off_rowp  = 128 * KB;                    // (M+1)*4
  const size_t off_curs  = off_rowp + 96 * KB;
  const size_t off_dinv  = off_curs + 96 * KB;
  const size_t off_meta  = off_dinv + 128 * KB;
  size_t off_wb = off_meta + (size_t)E * 8;
  off_wb = (off_wb + 255) & ~(size_t)255;
  const size_t off_h  = off_wb + 2 * MB;
  const size_t szHp   = (size_t)M * HP * 2;             // padded bf16 H
  const size_t off_xb = off_h + szHp;
  const size_t szXb   = (size_t)M * D_DIM * 2;

  const size_t need_fast   = off_h + szHp + 64 * KB;
  const size_t need_faster = off_xb + szXb + 64 * KB;

  if (ws_size >= need_fast && M > 256) {
    int*   flags   = (int*)(ws + off_flags);
    int*   cnt     = (int*)(ws + off_cnt);
    float* biasf   = (float*)(ws + off_biasf);
    int*   row_ptr = (int*)(ws + off_rowp);
    int*   cursor  = (int*)(ws + off_curs);
    float* dinv    = (float*)(ws + off_dinv);
    long long* meta = (long long*)(ws + off_meta);
    unsigned short* Wb = (unsigned short*)(ws + off_wb);
    __hip_bfloat16* H  = (__hip_bfloat16*)(ws + off_h);
    unsigned short* Xb = (unsigned short*)(ws + off_xb);

    detect_kernel<<<1, 256, 0, stream>>>((const unsigned int*)x,
                                         (const unsigned int*)Wm,
                                         (const unsigned int*)ei, (int*)flags);
    zero_cnt_kernel<<<(M + 255) / 256, 256, 0, stream>>>(cnt, M);
    count_deg_kernel<<<(E + 255) / 256, 256, 0, stream>>>(ei, E, flags, cnt);
    scan_kernel<<<1, 256, 0, stream>>>(cnt, M, row_ptr, cursor, dinv);
    scatter_kernel<<<(E + 255) / 256, 256, 0, stream>>>(ei, E, flags, dinv,
                                                        cursor, (int*)0, meta, 1);
    conv_w_kernel<<<(D_DIM * D_DIM) / 256, 256, 0, stream>>>(Wm, bias, flags,
                                                             Wb, biasf);
    const int mtiles = (M + 127) / 128;
    if (ws_size >= need_faster) {
      const int total8 = M * (D_DIM / 8);
      conv_x_kernel<<<(total8 + 255) / 256, 256, 0, stream>>>(x, flags, Xb,
                                                              total8);
      gemm_xw2_kernel<<<mtiles * 8, 256, 0, stream>>>(x, Xb, Wb, biasf, flags,
                                                      H, M);
    } else {
      dim3 ggrid(mtiles, D_DIM / 128);
      gemm_xw_kernel<<<ggrid, 256, 0, stream>>>(x, Wb, biasf, flags, H, M);
    }
    const int nodeblks = (M + 31) / 32;
    aggregate_h_slab_kernel<<<nodeblks * NSLAB, 256, 0, stream>>>(
        H, row_ptr, meta, dinv, flags, d_out, M, nodeblks);
  } else {
    // fallback layout (R4)
    int*   flags   = (int*)(ws);
    int*   cnt     = (int*)(ws + 4 * KB);
    int*   row_ptr = (int*)(ws + 128 * KB);
    int*   cursor  = (int*)(ws + 256 * KB);
    float* dinv    = (float*)(ws + 384 * KB);
    float* rowsum  = (float*)(ws + 512 * KB);
    float* biasf   = (float*)(ws + 640 * KB);
    int*   cols    = (int*)(ws + 768 * KB);
    unsigned short* Wb = (unsigned short*)(ws + 2 * MB);

    detect_kernel<<<1, 256, 0, stream>>>((const unsigned int*)x,
                                         (const unsigned int*)Wm,
                                         (const unsigned int*)ei, (int*)flags);
    zero_cnt_kernel<<<(M + 255) / 256, 256, 0, stream>>>(cnt, M);
    count_deg_kernel<<<(E + 255) / 256, 256, 0, stream>>>(ei, E, flags, cnt);
    scan_kernel<<<1, 256, 0, stream>>>(cnt, M, row_ptr, cursor, dinv);
    scatter_kernel<<<(E + 255) / 256, 256, 0, stream>>>(ei, E, flags, dinv,
                                                        cursor, cols, (long long*)0, 0);
    conv_w_kernel<<<(D_DIM * D_DIM) / 256, 256, 0, stream>>>(Wm, bias, flags,
                                                             Wb, biasf);
    aggregate_x_kernel<<<M, 256, 0, stream>>>(x, row_ptr, cols, dinv, flags,
                                              rowsum, d_out);
    strip_gemm_kernel<<<M / 32, 256, 0, stream>>>(d_out, Wb, biasf, rowsum,
                                                  flags, d_out);
  }
}

// Round 5
// 382.957 us; speedup vs baseline: 1.1553x; 1.1553x over previous
//
#include <hip/hip_runtime.h>
#include <hip/hip_bf16.h>
#include <stdint.h>
#include <stddef.h>

// GCNConv: out = S (X W^T + 1 b^T), S = D^-1/2 (A+I) D^-1/2
// Fast paths: Xb = bf16(X) [if ws allows]; H = Xb Wb^T + b via async MFMA GEMM
//   (128x128, BK=32, global_load_lds, XCD swizzle), H pitch padded to 1088
//   elems (2176B = 17 cache lines) to kill pow2 set-aliasing; then
//   column-slab aggregation with XCD-affinity: slab s is processed only by
//   blocks with blockIdx%8 == s%8, so each slab's 2.56MB line-set is filled
//   into exactly ONE XCD's L2 (fills ~41MB total instead of ~8x348MB).
//   Meta (8B col,w) is ~2.6MB -> L2-resident, read with NORMAL cached loads
//   (R3's nontemporal meta forced 16x HBM re-reads at full latency: 85->117us
//   regression). Out stores stay nontemporal (write-only).
// Fallback (small ws): aggregate-first + strip GEMM.
// Dtypes detected on device: flags[0] x fp32?, flags[1] W fp32?, flags[2] int64 edges?

#define D_DIM 1024
#define HP    1088            // padded H pitch in elements
#define HPB   2176u           // padded H pitch in bytes (17 * 128)
#define SLABW 64              // cols per slab = one 128B line
#define NSLAB (D_DIM / SLABW) // 16

typedef __bf16 bf16x8 __attribute__((ext_vector_type(8)));
typedef __bf16 bf16x4 __attribute__((ext_vector_type(4)));
typedef float  f32x4  __attribute__((ext_vector_type(4)));

#define GLOBAL_AS __attribute__((address_space(1)))
#define LDS_AS    __attribute__((address_space(3)))

static __device__ __forceinline__ void async_load16(const void* g, void* l) {
  __builtin_amdgcn_global_load_lds((GLOBAL_AS void*)(void*)g,
                                   (LDS_AS void*)l, 16, 0, 0);
}

// ---------------- dtype detection ----------------

__global__ void detect_kernel(const unsigned int* __restrict__ xw,
                              const unsigned int* __restrict__ ww,
                              const unsigned int* __restrict__ ew,
                              int* __restrict__ flags) {
  __shared__ int s[3];
  int t = threadIdx.x;
  if (t < 3) s[t] = 0;
  __syncthreads();
  int nx = 0, nw = 0, ze = 0;
  for (int i = t; i < 8192; i += 256) {
    if ((xw[i] & 0x7f80u) == 0x7f80u) nx++;
    if ((ww[i] & 0x7f80u) == 0x7f80u) nw++;
    if (ew[2 * i + 1] == 0u) ze++;
  }
  atomicAdd(&s[0], nx);
  atomicAdd(&s[1], nw);
  atomicAdd(&s[2], ze);
  __syncthreads();
  if (t == 0) {
    flags[0] = (s[0] >= 3) ? 1 : 0;
    flags[1] = (s[1] >= 3) ? 1 : 0;
    flags[2] = (s[2] >= 8000) ? 1 : 0;
  }
}

// ---------------- CSR construction ----------------

__global__ void zero_cnt_kernel(int* cnt, int n) {
  int i = blockIdx.x * blockDim.x + threadIdx.x;
  if (i < n) cnt[i] = 0;
}

__global__ void count_deg_kernel(const void* __restrict__ ei, int E,
                                 const int* __restrict__ flags,
                                 int* __restrict__ cnt) {
  int e = blockIdx.x * blockDim.x + threadIdx.x;
  if (e < E) {
    int r = flags[2] ? (int)((const long long*)ei)[e] : ((const int*)ei)[e];
    atomicAdd(&cnt[r], 1);
  }
}

// Single block, 256 threads; each thread owns a contiguous chunk.
__global__ void scan_kernel(const int* __restrict__ cnt, int n,
                            int* __restrict__ row_ptr, int* __restrict__ cursor,
                            float* __restrict__ dinv) {
  __shared__ int ssum[256];
  const int t = threadIdx.x;
  const int chunk = (n + 255) / 256;
  const int lo = t * chunk;
  const int hi = (lo + chunk < n) ? lo + chunk : n;
  int s = 0;
  for (int i = lo; i < hi; ++i) s += cnt[i];
  ssum[t] = s;
  __syncthreads();
  for (int off = 1; off < 256; off <<= 1) {
    int add = (t >= off) ? ssum[t - off] : 0;
    __syncthreads();
    ssum[t] += add;
    __syncthreads();
  }
  int run = ssum[t] - s;  // exclusive prefix of this thread's chunk
  for (int i = lo; i < hi; ++i) {
    int v = cnt[i];
    row_ptr[i] = run;
    cursor[i]  = run;
    dinv[i] = rsqrtf((float)(v + 1));
    run += v;
  }
  if (t == 255) row_ptr[n] = ssum[255];
}

// emit_w: store packed 8B meta { w:hi32, col:lo32 } (fast path).
// else:   store plain cols (fallback path).
__global__ void scatter_kernel(const void* __restrict__ ei, int E,
                               const int* __restrict__ flags,
                               const float* __restrict__ dinv,
                               int* __restrict__ cursor,
                               int* __restrict__ cols_out,
                               long long* __restrict__ meta, int emit_w) {
  int e = blockIdx.x * blockDim.x + threadIdx.x;
  if (e < E) {
    int r, c;
    if (flags[2]) {
      const long long* p = (const long long*)ei;
      r = (int)p[e]; c = (int)p[e + E];
    } else {
      const int* p = (const int*)ei;
      r = p[e]; c = p[e + E];
    }
    int pos = atomicAdd(&cursor[r], 1);
    if (emit_w) {
      float w = dinv[r] * dinv[c];
      unsigned long long mm =
          ((unsigned long long)__float_as_uint(w) << 32) | (unsigned)c;
      meta[pos] = (long long)mm;
    } else {
      cols_out[pos] = c;
    }
  }
}

// ---------------- canonicalize W (bf16) and bias (fp32) ----------------

__global__ void conv_w_kernel(const void* __restrict__ W,
                              const void* __restrict__ b,
                              const int* __restrict__ flags,
                              unsigned short* __restrict__ Wb,
                              float* __restrict__ biasf) {
  int i = blockIdx.x * blockDim.x + threadIdx.x;  // < 1M
  int wfp = flags[1];
  if (wfp) {
    __bf16 h = (__bf16)((const float*)W)[i];
    Wb[i] = *(unsigned short*)&h;
  } else {
    Wb[i] = ((const unsigned short*)W)[i];
  }
  if (i < D_DIM) {
    biasf[i] = wfp ? ((const float*)b)[i] : (float)((const __bf16*)b)[i];
  }
}

// ---------------- canonicalize X (bf16), faster path only ----------------

__global__ __launch_bounds__(256) void conv_x_kernel(
    const void* __restrict__ X, const int* __restrict__ flags,
    unsigned short* __restrict__ Xb, int total8) {
  int i = blockIdx.x * blockDim.x + threadIdx.x;
  if (i >= total8) return;
  if (!flags[0]) return;  // already bf16: gemm reads X directly
  const float* p = (const float*)X + (size_t)i * 8;
  f32x4 v0 = *(const f32x4*)p;
  f32x4 v1 = *(const f32x4*)(p + 4);
  bf16x8 r;
  r[0] = (__bf16)v0[0]; r[1] = (__bf16)v0[1];
  r[2] = (__bf16)v0[2]; r[3] = (__bf16)v0[3];
  r[4] = (__bf16)v1[0]; r[5] = (__bf16)v1[1];
  r[6] = (__bf16)v1[2]; r[7] = (__bf16)v1[3];
  *(bf16x8*)(Xb + (size_t)i * 8) = r;
}

// ================= FASTEST PATH GEMM =================
// H[M][HP] (bf16, padded pitch) = A * Wb^T + bias, A = bf16 X (Xb or X).
// 128x128 tile, BK=32, 4 waves 2x2, wave = 64x64 via 4x4 mfma 16x16x32.
// Both A and B staged with global_load_lds width=16 (linear LDS, bank-clean).
// 1-D grid, XCD-chunked swizzle, n-tile fastest.

__global__ __launch_bounds__(256) void gemm_xw2_kernel(
    const void* __restrict__ Xv,
    const unsigned short* __restrict__ Xb,
    const unsigned short* __restrict__ Wb,   // [1024][1024] bf16 [o][k]
    const float* __restrict__ biasf,
    const int* __restrict__ flags,
    __hip_bfloat16* __restrict__ H,          // [M][HP] bf16
    int M) {
  __shared__ unsigned short As[128 * 32];
  __shared__ unsigned short Bs[128 * 32];

  const int t    = threadIdx.x;
  const int lane = t & 63;
  const int wave = t >> 6;
  const int wm   = wave >> 1;
  const int wn   = wave & 1;

  const int nwg = gridDim.x;  // mtiles*8, divisible by 8
  const int wg  = (blockIdx.x & 7) * (nwg >> 3) + (blockIdx.x >> 3);
  const int m0  = (wg >> 3) * 128;
  const int n0  = (wg & 7) * 128;

  const unsigned short* Asrc =
      flags[0] ? Xb : (const unsigned short*)Xv;

  f32x4 acc[4][4] = {};

  const int ra = t >> 2;          // staging row 0..63 within half-tile
  const int kc = (t & 3) * 8;     // staging k-chunk (8 elems = 16B)
  int gr0 = m0 + ra;       if (gr0 >= M) gr0 = M - 1;   // clamp: dup row, masked at store
  int gr1 = m0 + 64 + ra;  if (gr1 >= M) gr1 = M - 1;
  const int quad = lane >> 4;
  const int mrow = lane & 15;

  for (int k0 = 0; k0 < D_DIM; k0 += 32) {
    async_load16(Asrc + (size_t)gr0 * D_DIM + k0 + kc, &As[ra * 32 + kc]);
    async_load16(Asrc + (size_t)gr1 * D_DIM + k0 + kc, &As[(ra + 64) * 32 + kc]);
    async_load16(Wb + (size_t)(n0 + ra) * D_DIM + k0 + kc, &Bs[ra * 32 + kc]);
    async_load16(Wb + (size_t)(n0 + ra + 64) * D_DIM + k0 + kc,
                 &Bs[(ra + 64) * 32 + kc]);
    __syncthreads();

    bf16x8 a[4], b[4];
#pragma unroll
    for (int i = 0; i < 4; ++i)
      a[i] = *(const bf16x8*)&As[(wm * 64 + i * 16 + mrow) * 32 + quad * 8];
#pragma unroll
    for (int j = 0; j < 4; ++j)
      b[j] = *(const bf16x8*)&Bs[(wn * 64 + j * 16 + mrow) * 32 + quad * 8];
#pragma unroll
    for (int i = 0; i < 4; ++i)
#pragma unroll
      for (int j = 0; j < 4; ++j)
        acc[i][j] = __builtin_amdgcn_mfma_f32_16x16x32_bf16(a[i], b[j], acc[i][j], 0, 0, 0);
    __syncthreads();
  }

  // epilogue: C/D layout col = lane&15 (=n), row = quad*4+reg (=m)
#pragma unroll
  for (int j = 0; j < 4; ++j) {
    int n = n0 + wn * 64 + j * 16 + mrow;
    float bn = biasf[n];
#pragma unroll
    for (int i = 0; i < 4; ++i) {
      int mb = m0 + wm * 64 + i * 16 + quad * 4;
#pragma unroll
      for (int rg = 0; rg < 4; ++rg) {
        int m = mb + rg;
        if (m < M) H[(size_t)m * HP + n] = __float2bfloat16(acc[i][j][rg] + bn);
      }
    }
  }
}

// ================= FAST PATH GEMM (manual A staging) =================

__global__ __launch_bounds__(256) void gemm_xw_kernel(
    const void* __restrict__ Xv,
    const unsigned short* __restrict__ Wb,   // [1024][1024] bf16 [o][k]
    const float* __restrict__ biasf,
    const int* __restrict__ flags,
    __hip_bfloat16* __restrict__ H,          // [M][HP] bf16
    int M) {
  __shared__ unsigned short As[128 * 32];
  __shared__ unsigned short Bs[128 * 32];

  const int t    = threadIdx.x;
  const int lane = t & 63;
  const int wave = t >> 6;
  const int wm   = wave >> 1;
  const int wn   = wave & 1;
  const int m0   = blockIdx.x * 128;
  const int n0   = blockIdx.y * 128;
  const int xfp  = flags[0];

  f32x4 acc[4][4] = {};

  const int ra = t >> 1;          // A-staging row 0..127
  const int kh = (t & 1) * 16;    // A-staging k-half (16 elems)
  const int rb = t >> 2;          // B-staging row 0..63
  const int kc = (t & 3) * 8;     // B-staging k-chunk (8 elems = 16B)
  const int quad = lane >> 4;
  const int mrow = lane & 15;

  for (int k0 = 0; k0 < D_DIM; k0 += 32) {
    async_load16(Wb + (size_t)(n0 + rb) * D_DIM + k0 + kc, &Bs[rb * 32 + kc]);
    async_load16(Wb + (size_t)(n0 + rb + 64) * D_DIM + k0 + kc,
                 &Bs[(rb + 64) * 32 + kc]);
    bf16x8 lo{}, hi{};
    int gm = m0 + ra;
    if (gm < M) {
      if (xfp) {
        const float* p = (const float*)Xv + (size_t)gm * D_DIM + k0 + kh;
        f32x4 v0 = *(const f32x4*)(p);
        f32x4 v1 = *(const f32x4*)(p + 4);
        f32x4 v2 = *(const f32x4*)(p + 8);
        f32x4 v3 = *(const f32x4*)(p + 12);
        lo[0] = (__bf16)v0[0]; lo[1] = (__bf16)v0[1];
        lo[2] = (__bf16)v0[2]; lo[3] = (__bf16)v0[3];
        lo[4] = (__bf16)v1[0]; lo[5] = (__bf16)v1[1];
        lo[6] = (__bf16)v1[2]; lo[7] = (__bf16)v1[3];
        hi[0] = (__bf16)v2[0]; hi[1] = (__bf16)v2[1];
        hi[2] = (__bf16)v2[2]; hi[3] = (__bf16)v2[3];
        hi[4] = (__bf16)v3[0]; hi[5] = (__bf16)v3[1];
        hi[6] = (__bf16)v3[2]; hi[7] = (__bf16)v3[3];
      } else {
        const unsigned short* p =
            (const unsigned short*)Xv + (size_t)gm * D_DIM + k0 + kh;
        lo = *(const bf16x8*)p;
        hi = *(const bf16x8*)(p + 8);
      }
    }
    *(bf16x8*)&As[ra * 32 + kh]     = lo;
    *(bf16x8*)&As[ra * 32 + kh + 8] = hi;
    __syncthreads();

    bf16x8 a[4], b[4];
#pragma unroll
    for (int i = 0; i < 4; ++i)
      a[i] = *(const bf16x8*)&As[(wm * 64 + i * 16 + mrow) * 32 + quad * 8];
#pragma unroll
    for (int j = 0; j < 4; ++j)
      b[j] = *(const bf16x8*)&Bs[(wn * 64 + j * 16 + mrow) * 32 + quad * 8];
#pragma unroll
    for (int i = 0; i < 4; ++i)
#pragma unroll
      for (int j = 0; j < 4; ++j)
        acc[i][j] = __builtin_amdgcn_mfma_f32_16x16x32_bf16(a[i], b[j], acc[i][j], 0, 0, 0);
    __syncthreads();
  }

#pragma unroll
  for (int j = 0; j < 4; ++j) {
    int n = n0 + wn * 64 + j * 16 + mrow;
    float bn = biasf[n];
#pragma unroll
    for (int i = 0; i < 4; ++i) {
      int mb = m0 + wm * 64 + i * 16 + quad * 4;
#pragma unroll
      for (int rg = 0; rg < 4; ++rg) {
        int m = mb + rg;
        if (m < M) H[(size_t)m * HP + n] = __float2bfloat16(acc[i][j][rg] + bn);
      }
    }
  }
}

// ---- Column-slab aggregation over padded H, XCD-affine ----
// out[i][slab] = dinv[i]^2 H[i][slab] + sum_e w_e H[col_e][slab]
// 16 slabs x 64 cols. All blocks of slab s have blockIdx%8 == s%8, so
// (with round-robin block->XCD dispatch) slab s lives on ONE XCD: its
// 2.56MB line-set is filled into that XCD's 4MB L2 exactly once and all
// gathers for the slab are local L2 hits. 2 passes (slabs 0-7, 8-15).
// Meta (~2.6MB) is L2-resident: plain cached loads (NOT nontemporal).
// Block = 256 thr = 32 nodes x 8 lanes; lane covers 16B of the 128B line.

__global__ __launch_bounds__(256) void aggregate_h_slab_kernel(
    const __hip_bfloat16* __restrict__ H,
    const int* __restrict__ row_ptr,
    const long long* __restrict__ meta,
    const float* __restrict__ dinv,
    const int* __restrict__ flags,
    void* __restrict__ outv, int M, int nodeblks) {
  // decode: blockIdx = pass*(nodeblks*8) + nb*8 + (slab&7); slab = pass*8+(slab&7)
  const int P    = nodeblks << 3;
  const int pass = blockIdx.x / P;
  const int rem  = blockIdx.x - pass * P;
  const int slab = (pass << 3) + (rem & 7);
  const int nb   = rem >> 3;
  const int t    = threadIdx.x;
  const int i    = nb * 32 + (t >> 3);
  if (i >= M) return;
  const int l = t & 7;
  const unsigned co = (unsigned)l * 16u;
  const char* Hs = (const char*)H + (unsigned)slab * 128u;

  float a[8];
  {
    float di = dinv[i];
    float w = di * di;
    bf16x8 v = *(const bf16x8*)(Hs + (unsigned)i * HPB + co);
#pragma unroll
    for (int k = 0; k < 8; ++k) a[k] = w * (float)v[k];
  }

  const int e0 = row_ptr[i], e1 = row_ptr[i + 1];
  int e = e0;
  for (; e + 4 <= e1; e += 4) {
    long long m0 = meta[e];
    long long m1 = meta[e + 1];
    long long m2 = meta[e + 2];
    long long m3 = meta[e + 3];
    unsigned o0 = (unsigned)(m0 & 0xffffffffLL) * HPB + co;
    unsigned o1 = (unsigned)(m1 & 0xffffffffLL) * HPB + co;
    unsigned o2 = (unsigned)(m2 & 0xffffffffLL) * HPB + co;
    unsigned o3 = (unsigned)(m3 & 0xffffffffLL) * HPB + co;
    float w0 = __uint_as_float((unsigned)((unsigned long long)m0 >> 32));
    float w1 = __uint_as_float((unsigned)((unsigned long long)m1 >> 32));
    float w2 = __uint_as_float((unsigned)((unsigned long long)m2 >> 32));
    float w3 = __uint_as_float((unsigned)((unsigned long long)m3 >> 32));
    bf16x8 u0 = *(const bf16x8*)(Hs + o0);
    bf16x8 u1 = *(const bf16x8*)(Hs + o1);
    bf16x8 u2 = *(const bf16x8*)(Hs + o2);
    bf16x8 u3 = *(const bf16x8*)(Hs + o3);
#pragma unroll
    for (int q = 0; q < 8; ++q) {
      a[q] = fmaf(w0, (float)u0[q],
             fmaf(w1, (float)u1[q],
             fmaf(w2, (float)u2[q],
             fmaf(w3, (float)u3[q], a[q]))));
    }
  }
  for (; e < e1; ++e) {
    long long m0 = meta[e];
    unsigned o0 = (unsigned)(m0 & 0xffffffffLL) * HPB + co;
    float w0 = __uint_as_float((unsigned)((unsigned long long)m0 >> 32));
    bf16x8 u0 = *(const bf16x8*)(Hs + o0);
#pragma unroll
    for (int q = 0; q < 8; ++q) a[q] = fmaf(w0, (float)u0[q], a[q]);
  }

  if (flags[0]) {
    float* o = (float*)outv + (size_t)i * D_DIM + slab * SLABW + l * 8;
    f32x4 r0, r1;
    r0[0] = a[0]; r0[1] = a[1]; r0[2] = a[2]; r0[3] = a[3];
    r1[0] = a[4]; r1[1] = a[5]; r1[2] = a[6]; r1[3] = a[7];
    __builtin_nontemporal_store(r0, (f32x4*)o);
    __builtin_nontemporal_store(r1, (f32x4*)(o + 4));
  } else {
    __hip_bfloat16* o =
        (__hip_bfloat16*)outv + (size_t)i * D_DIM + slab * SLABW + l * 8;
    bf16x8 r;
#pragma unroll
    for (int k = 0; k < 8; ++k) r[k] = (__bf16)a[k];
    __builtin_nontemporal_store(*(f32x4*)&r, (f32x4*)o);
  }
}

// ================= FALLBACK PATH (R4, proven) =================

__global__ __launch_bounds__(256) void aggregate_x_kernel(
    const void* __restrict__ X,
    const int* __restrict__ row_ptr,
    const int* __restrict__ cols,
    const float* __restrict__ dinv,
    const int* __restrict__ flags,
    float* __restrict__ rowsum,
    void* __restrict__ Y) {
  const int i  = blockIdx.x;
  const int c0 = threadIdx.x * 4;
  const float di = dinv[i];
  const int e0 = row_ptr[i], e1 = row_ptr[i + 1];
  float wsum = di * di;
  float a0, a1, a2, a3;

  if (flags[0]) {
    const float* Xf = (const float*)X;
    f32x4 v = *(const f32x4*)(Xf + (size_t)i * D_DIM + c0);
    a0 = wsum * v[0]; a1 = wsum * v[1]; a2 = wsum * v[2]; a3 = wsum * v[3];
    for (int e = e0; e < e1; ++e) {
      int c = cols[e];
      float w = di * dinv[c];
      wsum += w;
      f32x4 u = *(const f32x4*)(Xf + (size_t)c * D_DIM + c0);
      a0 += w * u[0]; a1 += w * u[1]; a2 += w * u[2]; a3 += w * u[3];
    }
    f32x4 r; r[0] = a0; r[1] = a1; r[2] = a2; r[3] = a3;
    *(f32x4*)((float*)Y + (size_t)i * D_DIM + c0) = r;
  } else {
    const __hip_bfloat16* Xb = (const __hip_bfloat16*)X;
    bf16x4 v = *(const bf16x4*)(Xb + (size_t)i * D_DIM + c0);
    a0 = wsum * (float)v[0]; a1 = wsum * (float)v[1];
    a2 = wsum * (float)v[2]; a3 = wsum * (float)v[3];
    for (int e = e0; e < e1; ++e) {
      int c = cols[e];
      float w = di * dinv[c];
      wsum += w;
      bf16x4 u = *(const bf16x4*)(Xb + (size_t)c * D_DIM + c0);
      a0 += w * (float)u[0]; a1 += w * (float)u[1];
      a2 += w * (float)u[2]; a3 += w * (float)u[3];
    }
    bf16x4 r;
    r[0] = (__bf16)a0; r[1] = (__bf16)a1; r[2] = (__bf16)a2; r[3] = (__bf16)a3;
    *(bf16x4*)((__hip_bfloat16*)Y + (size_t)i * D_DIM + c0) = r;
  }
  if (threadIdx.x == 0) rowsum[i] = wsum;
}

__global__ __launch_bounds__(256) void strip_gemm_kernel(
    const void* __restrict__ Yv,
    const unsigned short* __restrict__ Wb,
    const float* __restrict__ biasf,
    const float* __restrict__ rowsum,
    const int* __restrict__ flags,
    void* __restrict__ outv) {
  __shared__ unsigned short Ys[32 * 1024];

  const int t    = threadIdx.x;
  const int lane = t & 63;
  const int wave = t >> 6;
  const int m0   = blockIdx.x * 32;
  const int ofp  = flags[0];

  if (ofp) {
    const float* Yf = (const float*)Yv;
    for (int idx = t; idx < 32 * 128; idx += 256) {
      int r = idx >> 7, c = idx & 127;
      const float* p = Yf + (size_t)(m0 + r) * D_DIM + c * 8;
      f32x4 lo = *(const f32x4*)p;
      f32x4 hi = *(const f32x4*)(p + 4);
      bf16x8 v;
      v[0] = (__bf16)lo[0]; v[1] = (__bf16)lo[1];
      v[2] = (__bf16)lo[2]; v[3] = (__bf16)lo[3];
      v[4] = (__bf16)hi[0]; v[5] = (__bf16)hi[1];
      v[6] = (__bf16)hi[2]; v[7] = (__bf16)hi[3];
      int sc = c ^ (r & 15);
      *(bf16x8*)&Ys[r * 1024 + sc * 8] = v;
    }
  } else {
    const __hip_bfloat16* Yb = (const __hip_bfloat16*)Yv;
    for (int idx = t; idx < 32 * 128; idx += 256) {
      int r = idx >> 7, c = idx & 127;
      bf16x8 v = *(const bf16x8*)(Yb + (size_t)(m0 + r) * D_DIM + c * 8);
      int sc = c ^ (r & 15);
      *(bf16x8*)&Ys[r * 1024 + sc * 8] = v;
    }
  }
  __syncthreads();

  const int quad = lane >> 4;
  const int mrow = lane & 15;

  for (int nb = 0; nb < 4; ++nb) {
    f32x4 acc[2][4] = {};
    for (int k0 = 0; k0 < D_DIM; k0 += 32) {
      const int cbase = k0 >> 3;
      bf16x8 a[2], b[4];
#pragma unroll
      for (int i = 0; i < 2; ++i) {
        int m = i * 16 + mrow;
        int sc = (cbase + quad) ^ mrow;
        a[i] = *(const bf16x8*)&Ys[m * 1024 + sc * 8];
      }
#pragma unroll
      for (int j = 0; j < 4; ++j) {
        int n = wave * 256 + nb * 64 + j * 16 + mrow;
        b[j] = *(const bf16x8*)(Wb + (size_t)n * D_DIM + k0 + quad * 8);
      }
#pragma unroll
      for (int i = 0; i < 2; ++i)
#pragma unroll
        for (int j = 0; j < 4; ++j)
          acc[i][j] = __builtin_amdgcn_mfma_f32_16x16x32_bf16(a[i], b[j], acc[i][j], 0, 0, 0);
    }
#pragma unroll
    for (int j = 0; j < 4; ++j) {
      int n = wave * 256 + nb * 64 + j * 16 + mrow;
      float bn = biasf[n];
#pragma unroll
      for (int i = 0; i < 2; ++i) {
        int mb = m0 + i * 16 + quad * 4;
#pragma unroll
        for (int rg = 0; rg < 4; ++rg) {
          int m = mb + rg;
          float val = acc[i][j][rg] + rowsum[m] * bn;
          if (ofp) ((float*)outv)[(size_t)m * D_DIM + n] = val;
          else ((__hip_bfloat16*)outv)[(size_t)m * D_DIM + n] = __float2bfloat16(val);
        }
      }
    }
  }
}

// ---------------- launch ----------------

extern "C" void kernel_launch(void* const* d_in, const int* in_sizes, int n_in,
                              void* d_out, int out_size, void* d_ws, size_t ws_size,
                              hipStream_t stream) {
  const void* x    = d_in[0];
  const void* ei   = d_in[1];
  const void* Wm   = d_in[2];
  const void* bias = d_in[3];

  const int E = in_sizes[1] / 2;
  const int M = in_sizes[0] / D_DIM;

  char* ws = (char*)d_ws;
  const size_t KB = 1024, MB = 1024 * 1024;

  // fast-path layout (runtime offsets; meta sized by E)
  const size_t off_flags = 0;
  const size_t off_cnt   = 4 * KB;
  const size_t off_biasf = 96 * KB;
  const size_t off_rowp  = 128 * KB;                    // (M+1)*4
  const size_t off_curs  = off_rowp + 96 * KB;
  const size_t off_dinv  = off_curs + 96 * KB;
  const size_t off_meta  = off_dinv + 128 * KB;
  size_t off_wb = off_meta + (size_t)E * 8;
  off_wb = (off_wb + 255) & ~(size_t)255;
  const size_t off_h  = off_wb + 2 * MB;
  const size_t szHp   = (size_t)M * HP * 2;             // padded bf16 H
  const size_t off_xb = off_h + szHp;
  const size_t szXb   = (size_t)M * D_DIM * 2;

  const size_t need_fast   = off_h + szHp + 64 * KB;
  const size_t need_faster = off_xb + szXb + 64 * KB;

  if (ws_size >= need_fast && M > 256) {
    int*   flags   = (int*)(ws + off_flags);
    int*   cnt     = (int*)(ws + off_cnt);
    float* biasf   = (float*)(ws + off_biasf);
    int*   row_ptr = (int*)(ws + off_rowp);
    int*   cursor  = (int*)(ws + off_curs);
    float* dinv    = (float*)(ws + off_dinv);
    long long* meta = (long long*)(ws + off_meta);
    unsigned short* Wb = (unsigned short*)(ws + off_wb);
    __hip_bfloat16* H  = (__hip_bfloat16*)(ws + off_h);
    unsigned short* Xb = (unsigned short*)(ws + off_xb);

    detect_kernel<<<1, 256, 0, stream>>>((const unsigned int*)x,
                                         (const unsigned int*)Wm,
                                         (const unsigned int*)ei, (int*)flags);
    zero_cnt_kernel<<<(M + 255) / 256, 256, 0, stream>>>(cnt, M);
    count_deg_kernel<<<(E + 255) / 256, 256, 0, stream>>>(ei, E, flags, cnt);
    scan_kernel<<<1, 256, 0, stream>>>(cnt, M, row_ptr, cursor, dinv);
    scatter_kernel<<<(E + 255) / 256, 256, 0, stream>>>(ei, E, flags, dinv,
                                                        cursor, (int*)0, meta, 1);
    conv_w_kernel<<<(D_DIM * D_DIM) / 256, 256, 0, stream>>>(Wm, bias, flags,
                                                             Wb, biasf);
    const int mtiles = (M + 127) / 128;
    if (ws_size >= need_faster) {
      const int total8 = M * (D_DIM / 8);
      conv_x_kernel<<<(total8 + 255) / 256, 256, 0, stream>>>(x, flags, Xb,
                                                              total8);
      gemm_xw2_kernel<<<mtiles * 8, 256, 0, stream>>>(x, Xb, Wb, biasf, flags,
                                                      H, M);
    } else {
      dim3 ggrid(mtiles, D_DIM / 128);
      gemm_xw_kernel<<<ggrid, 256, 0, stream>>>(x, Wb, biasf, flags, H, M);
    }
    const int nodeblks = (M + 31) / 32;
    aggregate_h_slab_kernel<<<nodeblks * NSLAB, 256, 0, stream>>>(
        H, row_ptr, meta, dinv, flags, d_out, M, nodeblks);
  } else {
    // fallback layout (R4)
    int*   flags   = (int*)(ws);
    int*   cnt     = (int*)(ws + 4 * KB);
    int*   row_ptr = (int*)(ws + 128 * KB);
    int*   cursor  = (int*)(ws + 256 * KB);
    float* dinv    = (float*)(ws + 384 * KB);
    float* rowsum  = (float*)(ws + 512 * KB);
    float* biasf   = (float*)(ws + 640 * KB);
    int*   cols    = (int*)(ws + 768 * KB);
    unsigned short* Wb = (unsigned short*)(ws + 2 * MB);

    detect_kernel<<<1, 256, 0, stream>>>((const unsigned int*)x,
                                         (const unsigned int*)Wm,
                                         (const unsigned int*)ei, (int*)flags);
    zero_cnt_kernel<<<(M + 255) / 256, 256, 0, stream>>>(cnt, M);
    count_deg_kernel<<<(E + 255) / 256, 256, 0, stream>>>(ei, E, flags, cnt);
    scan_kernel<<<1, 256, 0, stream>>>(cnt, M, row_ptr, cursor, dinv);
    scatter_kernel<<<(E + 255) / 256, 256, 0, stream>>>(ei, E, flags, dinv,
                                                        cursor, cols, (long long*)0, 0);
    conv_w_kernel<<<(D_DIM * D_DIM) / 256, 256, 0, stream>>>(Wm, bias, flags,
                                                             Wb, biasf);
    aggregate_x_kernel<<<M, 256, 0, stream>>>(x, row_ptr, cols, dinv, flags,
                                              rowsum, d_out);
    strip_gemm_kernel<<<M / 32, 256, 0, stream>>>(d_out, Wb, biasf, rowsum,
                                                  flags, d_out);
  }
}